// Round 6
// baseline (121.044 us; speedup 1.0000x reference)
//
#include <hip/hip_runtime.h>
#include <math.h>

// MultiHeadsGATLayer — algebraic reduction, 4 stream-ordered dispatches.
//   s_src[h][n] = x[n] . (W_heads[h] @ a_src[h]),  s_dst likewise
//   atts = lrelu(s_src[e0]+s_dst[e1]); mt = sum_h atts*lin_w + lin_b
//   out = colwise sparse softmax; non-edge cells underflow to 0 in f32.
// Fixed-stride (CAP=128) col/row slots + atomic cursors (no histogram/scan/
// memset). K4 is LDS-free: coalesced float4 zero-stream, barrier (drains
// stores), then overwrite ~32 nonzero cells while lines sit in L2.
// (R4 lesson: cooperative grid.sync ~120us/sync on 8-XCD — avoid.)

#define ALPHA 0.2f
constexpr int S = 128;
constexpr int O = 64;
constexpr int H = 4;
constexpr int CAP = 128;    // slots per column/row (degree ~ Poisson(32))
constexpr int RPB = 4;      // rows per block in K4

// --- K1: wvec fold (per-block, tiny) + per-node scores (float4 layout) + zero cursors ---
__global__ void __launch_bounds__(256) k1_scores(
    const float* __restrict__ x, const float* __restrict__ W, const float* __restrict__ a,
    float4* __restrict__ s_src4, float4* __restrict__ s_dst4,
    int* __restrict__ col_cursor, int* __restrict__ row_cursor, int* __restrict__ empty_cnt,
    int N)
{
    __shared__ float wsbuf[2 * H * S];
    int tid = threadIdx.x;
    for (int t = tid; t < 2 * H * S; t += 256) {
        int which = t / (H * S);           // 0 = src half, 1 = dst half
        int hs = t % (H * S);
        int h = hs / S, s = hs % S;
        const float* Wr = W + ((size_t)h * S + s) * O;
        const float* av = a + h * 2 * O + which * O;
        float acc = 0.f;
        for (int o = 0; o < O; ++o) acc += Wr[o] * av[o];
        wsbuf[t] = acc;
    }
    __syncthreads();
    int n = blockIdx.x * 256 + tid;
    if (n == 0) empty_cnt[0] = 0;
    if (n >= N) return;
    col_cursor[n] = 0;
    row_cursor[n] = 0;
    const float* wsrc = wsbuf;
    const float* wdst = wsbuf + H * S;
    const float4* xr = (const float4*)(x + (size_t)n * S);
    float accs[H] = {0, 0, 0, 0}, accd[H] = {0, 0, 0, 0};
    for (int i = 0; i < S / 4; ++i) {
        float4 v = xr[i];
#pragma unroll
        for (int h = 0; h < H; ++h) {
            const float* p = wsrc + h * S + i * 4;
            const float* q = wdst + h * S + i * 4;
            accs[h] += v.x * p[0] + v.y * p[1] + v.z * p[2] + v.w * p[3];
            accd[h] += v.x * q[0] + v.y * q[1] + v.z * q[2] + v.w * q[3];
        }
    }
    s_src4[n] = make_float4(accs[0], accs[1], accs[2], accs[3]);
    s_dst4[n] = make_float4(accd[0], accd[1], accd[2], accd[3]);
}

// --- K2: per-edge logit + head combine -> col slots (int4) + row link ---
__global__ void __launch_bounds__(256) k2_scatter(
    const int* __restrict__ edges, const float* __restrict__ values,
    const float4* __restrict__ s_src4, const float4* __restrict__ s_dst4,
    const float* __restrict__ lin_w, const float* __restrict__ lin_b,
    int* __restrict__ col_cursor, int* __restrict__ row_cursor,
    int4* __restrict__ col_ent, int* __restrict__ col_r, int N, int E)
{
    int e = blockIdx.x * 256 + threadIdx.x;
    if (e >= E) return;
    int r = edges[e];
    int c = edges[(size_t)E + e];
    if ((unsigned)r >= (unsigned)N || (unsigned)c >= (unsigned)N) return;
    float4 ss = s_src4[r];
    float4 sd = s_dst4[c];
    float att0 = ss.x + sd.x, att1 = ss.y + sd.y, att2 = ss.z + sd.z, att3 = ss.w + sd.w;
    att0 = att0 >= 0.f ? att0 : ALPHA * att0;
    att1 = att1 >= 0.f ? att1 : ALPHA * att1;
    att2 = att2 >= 0.f ? att2 : ALPHA * att2;
    att3 = att3 >= 0.f ? att3 : ALPHA * att3;
    float mt = lin_b[0] + att0 * lin_w[0] + att1 * lin_w[1] + att2 * lin_w[2] + att3 * lin_w[3];
    float av = values[e];
    float nv = av * mt;
    int posc = atomicAdd(&col_cursor[c], 1);
    int posr = atomicAdd(&row_cursor[r], 1);
    if (posc < CAP && posr < CAP) {
        int4 ent;
        ent.x = r;
        ent.y = __float_as_int(nv);
        ent.z = __float_as_int(av);
        ent.w = r * CAP + posr;            // row-slot link
        col_ent[(size_t)c * CAP + posc] = ent;
        col_r[(size_t)r * CAP + posr] = c;
    }
}

// --- K3: per-column sparse softmax (one wave/column, registers for m<=64) ---
__global__ void __launch_bounds__(256) k3_softmax(
    const int4* __restrict__ col_ent, const int* __restrict__ col_cursor,
    float* __restrict__ val_r, int* __restrict__ empty_list, int* __restrict__ empty_cnt,
    int N)
{
    int wave = threadIdx.x >> 6, lane = threadIdx.x & 63;
    int j = blockIdx.x * 4 + wave;
    if (j >= N) return;
    int m = col_cursor[j];
    if (m > CAP) m = CAP;
    if (m == 0) {
        if (lane == 0) { int p = atomicAdd(empty_cnt, 1); empty_list[p] = j; }
        return;
    }
    const int4* base = col_ent + (size_t)j * CAP;
    if (m <= 64) {
        bool mine = lane < m;
        int r; float v, av; int link = 0;
        if (mine) {
            int4 ent = base[lane];
            r = ent.x; v = __int_as_float(ent.y); av = __int_as_float(ent.z); link = ent.w;
        } else {
            r = -1 - lane; v = 0.f; av = 0.f;   // unique sentinels
        }
        float dsum = 0.f, asum = 0.f;
        bool first = true;
        for (int l = 0; l < 64; ++l) {
            int rl = __shfl(r, l);
            float vl = __shfl(v, l);
            float al = __shfl(av, l);
            if (rl == r) {
                dsum += vl; asum += al;
                if (l < lane) first = false;
            }
        }
        float mask = (asum == 1.0f) ? 0.f : asum;   // a_dense==1 -> 0, else count
        float val = dsum + mask;
        float lmax = (mine && first) ? val : -INFINITY;
#pragma unroll
        for (int off = 32; off; off >>= 1) lmax = fmaxf(lmax, __shfl_xor(lmax, off));
        float ex = (mine && first) ? expf(val - lmax) : 0.f;   // count each group once
        float lsum = ex;
#pragma unroll
        for (int off = 32; off; off >>= 1) lsum += __shfl_xor(lsum, off);
        float inv = 1.0f / lsum;
        // dup group members hold identical val -> idempotent row-slot writes
        if (mine) val_r[link] = expf(val - lmax) * inv;
    } else {
        // robust path (column degree > 64; ~never at Poisson(32)) — O(m^2)
        float lmax = -INFINITY;
        for (int k = lane; k < m; k += 64) {
            int rk = base[k].x;
            bool first = true;
            float ds = 0.f, as = 0.f;
            for (int l = 0; l < m; ++l) {
                int4 el = base[l];
                if (el.x == rk) {
                    if (l < k) first = false;
                    ds += __int_as_float(el.y);
                    as += __int_as_float(el.z);
                }
            }
            if (first) {
                float mk = (as == 1.0f) ? 0.f : as;
                lmax = fmaxf(lmax, ds + mk);
            }
        }
#pragma unroll
        for (int off = 32; off; off >>= 1) lmax = fmaxf(lmax, __shfl_xor(lmax, off));
        float lsum = 0.f;
        for (int k = lane; k < m; k += 64) {
            int rk = base[k].x;
            bool first = true;
            float ds = 0.f, as = 0.f;
            for (int l = 0; l < m; ++l) {
                int4 el = base[l];
                if (el.x == rk) {
                    if (l < k) first = false;
                    ds += __int_as_float(el.y);
                    as += __int_as_float(el.z);
                }
            }
            if (first) {
                float mk = (as == 1.0f) ? 0.f : as;
                lsum += expf(ds + mk - lmax);
            }
        }
#pragma unroll
        for (int off = 32; off; off >>= 1) lsum += __shfl_xor(lsum, off);
        float inv = 1.0f / lsum;
        for (int k = lane; k < m; k += 64) {
            int rk = base[k].x;
            float ds = 0.f, as = 0.f;
            for (int l = 0; l < m; ++l) {
                int4 el = base[l];
                if (el.x == rk) {
                    ds += __int_as_float(el.y);
                    as += __int_as_float(el.z);
                }
            }
            float mk = (as == 1.0f) ? 0.f : as;
            val_r[base[k].w] = expf(ds + mk - lmax) * inv;   // idempotent for dups
        }
    }
}

// --- K4: LDS-free row write — coalesced zero stream, barrier, overwrite nonzeros ---
// __syncthreads drains vmcnt before s_barrier (compiler-enforced), so the
// zero-stores are at the coherence point before the scalar overwrites issue.
__global__ void __launch_bounds__(256) k4_rowwrite(
    const int* __restrict__ col_r, const float* __restrict__ val_r,
    const int* __restrict__ row_cursor, const int* __restrict__ empty_list,
    const int* __restrict__ empty_cnt, float* __restrict__ out, int N)
{
    int t = threadIdx.x;
    const float4 z4 = make_float4(0.f, 0.f, 0.f, 0.f);
    int ec = empty_cnt[0];
    float u = 1.0f / (float)N;
    int n4 = N / 4;
#pragma unroll
    for (int q = 0; q < RPB; ++q) {
        int i = blockIdx.x * RPB + q;
        if (i >= N) return;
        float* orow = out + (size_t)i * N;
        float4* o4 = (float4*)orow;
        for (int k = t; k < n4; k += 256) o4[k] = z4;
        __syncthreads();   // zeros complete before overwrites (and next row's zeros)
        int mr = row_cursor[i];
        if (mr > CAP) mr = CAP;
        const int* cr = col_r + (size_t)i * CAP;
        const float* vr = val_r + (size_t)i * CAP;
        for (int k = t; k < mr; k += 256) orow[cr[k]] = vr[k];
        for (int k = t; k < ec; k += 256) orow[empty_list[k]] = u;
    }
}

extern "C" void kernel_launch(void* const* d_in, const int* in_sizes, int n_in,
                              void* d_out, int out_size, void* d_ws, size_t ws_size,
                              hipStream_t stream) {
    const float* x = (const float*)d_in[0];
    const int* edges = (const int*)d_in[1];      // harness: integer inputs are int32
    const float* values = (const float*)d_in[2];
    const float* W = (const float*)d_in[3];
    const float* a = (const float*)d_in[4];
    const float* lin_w = (const float*)d_in[5];
    const float* lin_b = (const float*)d_in[6];
    float* out = (float*)d_out;

    int N = in_sizes[0] / S;   // 8192
    int E = in_sizes[2];       // 262144

    // workspace carve (256B-aligned slabs)
    char* wsb = (char*)d_ws;
    size_t off = 0;
    auto alloc = [&](size_t bytes) -> void* {
        void* p = wsb + off;
        off += (bytes + 255) & ~(size_t)255;
        return p;
    };
    float4* s_src4 = (float4*)alloc((size_t)N * 16);
    float4* s_dst4 = (float4*)alloc((size_t)N * 16);
    int* col_cursor = (int*)alloc((size_t)N * 4);
    int* row_cursor = (int*)alloc((size_t)N * 4);
    int* empty_cnt = (int*)alloc(256);
    int* empty_list = (int*)alloc((size_t)N * 4);
    int4* col_ent = (int4*)alloc((size_t)N * CAP * 16);
    int* col_r = (int*)alloc((size_t)N * CAP * 4);
    float* val_r = (float*)alloc((size_t)N * CAP * 4);

    k1_scores<<<(N + 255) / 256, 256, 0, stream>>>(x, W, a, s_src4, s_dst4,
                                                   col_cursor, row_cursor, empty_cnt, N);
    k2_scatter<<<(E + 255) / 256, 256, 0, stream>>>(edges, values, s_src4, s_dst4, lin_w, lin_b,
                                                    col_cursor, row_cursor, col_ent, col_r, N, E);
    k3_softmax<<<(N + 3) / 4, 256, 0, stream>>>(col_ent, col_cursor, val_r,
                                                empty_list, empty_cnt, N);
    k4_rowwrite<<<(N + RPB - 1) / RPB, 256, 0, stream>>>(col_r, val_r, row_cursor,
                                                         empty_list, empty_cnt, out, N);
}

// Round 7
// 102.709 us; speedup vs baseline: 1.1785x; 1.1785x over previous
//
#include <hip/hip_runtime.h>
#include <math.h>

// MultiHeadsGATLayer — algebraic reduction, 3 stream-ordered dispatches.
//   s_src[h][n] = x[n] . (W_heads[h] @ a_src[h]),  s_dst likewise
//   atts = lrelu(s_src[e0]+s_dst[e1]); mt = sum_h atts*lin_w + lin_b
//   out = colwise sparse softmax; non-edge cells underflow to 0 in f32.
// K1 zeroes the 268MB output (no deps -> front of pipe) + scores + cursors.
// K2 scatters edges to fixed-stride col slots. K3 does per-column softmax and
// writes results DIRECTLY to out (scattered dwords hit zeroed lines; ~33MB RFO).
// (R4 lesson: cooperative grid.sync ~120us/sync on 8-XCD. R6 lesson: LDS
// round-trip in the row-writer was free — the store stream is the cost.)

#define ALPHA 0.2f
constexpr int S = 128;
constexpr int O = 64;
constexpr int H = 4;
constexpr int CAP = 128;    // slots per column (degree ~ Poisson(32))

// --- K1: zero output stream + wvec fold + per-node scores + zero cursors ---
__global__ void __launch_bounds__(256) k1_zero_scores(
    const float* __restrict__ x, const float* __restrict__ W, const float* __restrict__ a,
    float4* __restrict__ s_src4, float4* __restrict__ s_dst4,
    int* __restrict__ col_cursor, float4* __restrict__ out4,
    int N, size_t n4tot)
{
    __shared__ float wsbuf[2 * H * S];
    int tid = threadIdx.x;
    int gt = blockIdx.x * 256 + tid;

    // scores job: only the first N/256 blocks participate
    if (blockIdx.x * 256 < N) {
        for (int t = tid; t < 2 * H * S; t += 256) {
            int which = t / (H * S);           // 0 = src half, 1 = dst half
            int hs = t % (H * S);
            int h = hs / S, s = hs % S;
            const float* Wr = W + ((size_t)h * S + s) * O;
            const float* av = a + h * 2 * O + which * O;
            float acc = 0.f;
            for (int o = 0; o < O; ++o) acc += Wr[o] * av[o];
            wsbuf[t] = acc;
        }
        __syncthreads();
        int n = gt;
        if (n < N) {
            col_cursor[n] = 0;
            const float* wsrc = wsbuf;
            const float* wdst = wsbuf + H * S;
            const float4* xr = (const float4*)(x + (size_t)n * S);
            float accs[H] = {0, 0, 0, 0}, accd[H] = {0, 0, 0, 0};
            for (int i = 0; i < S / 4; ++i) {
                float4 v = xr[i];
#pragma unroll
                for (int h = 0; h < H; ++h) {
                    const float* p = wsrc + h * S + i * 4;
                    const float* q = wdst + h * S + i * 4;
                    accs[h] += v.x * p[0] + v.y * p[1] + v.z * p[2] + v.w * p[3];
                    accd[h] += v.x * q[0] + v.y * q[1] + v.z * q[2] + v.w * q[3];
                }
            }
            s_src4[n] = make_float4(accs[0], accs[1], accs[2], accs[3]);
            s_dst4[n] = make_float4(accd[0], accd[1], accd[2], accd[3]);
        }
    }

    // zero-stream job: all blocks, grid-stride float4
    const float4 z4 = make_float4(0.f, 0.f, 0.f, 0.f);
    size_t GT = (size_t)gridDim.x * 256;
    for (size_t k = gt; k < n4tot; k += GT) out4[k] = z4;
}

// --- K2: per-edge logit + head combine -> fixed-stride col slots (int4) ---
__global__ void __launch_bounds__(256) k2_scatter(
    const int* __restrict__ edges, const float* __restrict__ values,
    const float4* __restrict__ s_src4, const float4* __restrict__ s_dst4,
    const float* __restrict__ lin_w, const float* __restrict__ lin_b,
    int* __restrict__ col_cursor, int4* __restrict__ col_ent, int N, int E)
{
    int e = blockIdx.x * 256 + threadIdx.x;
    if (e >= E) return;
    int r = edges[e];
    int c = edges[(size_t)E + e];
    if ((unsigned)r >= (unsigned)N || (unsigned)c >= (unsigned)N) return;
    float4 ss = s_src4[r];
    float4 sd = s_dst4[c];
    float att0 = ss.x + sd.x, att1 = ss.y + sd.y, att2 = ss.z + sd.z, att3 = ss.w + sd.w;
    att0 = att0 >= 0.f ? att0 : ALPHA * att0;
    att1 = att1 >= 0.f ? att1 : ALPHA * att1;
    att2 = att2 >= 0.f ? att2 : ALPHA * att2;
    att3 = att3 >= 0.f ? att3 : ALPHA * att3;
    float mt = lin_b[0] + att0 * lin_w[0] + att1 * lin_w[1] + att2 * lin_w[2] + att3 * lin_w[3];
    float av = values[e];
    float nv = av * mt;
    int posc = atomicAdd(&col_cursor[c], 1);
    if (posc < CAP) {
        int4 ent;
        ent.x = r;
        ent.y = __float_as_int(nv);
        ent.z = __float_as_int(av);
        ent.w = 0;
        col_ent[(size_t)c * CAP + posc] = ent;
    }
}

// --- K3: per-column sparse softmax, direct scattered writes into out ---
__global__ void __launch_bounds__(256) k3_softmax(
    const int4* __restrict__ col_ent, const int* __restrict__ col_cursor,
    float* __restrict__ out, int N)
{
    int wave = threadIdx.x >> 6, lane = threadIdx.x & 63;
    int j = blockIdx.x * 4 + wave;
    if (j >= N) return;
    int m = col_cursor[j];
    if (m > CAP) m = CAP;
    if (m == 0) {
        // empty column: all entries -1e9 -> uniform softmax over the column
        float u = 1.0f / (float)N;
        for (int i = lane; i < N; i += 64) out[(size_t)i * N + j] = u;
        return;
    }
    const int4* base = col_ent + (size_t)j * CAP;
    if (m <= 64) {
        bool mine = lane < m;
        int r; float v, av;
        if (mine) {
            int4 ent = base[lane];
            r = ent.x; v = __int_as_float(ent.y); av = __int_as_float(ent.z);
        } else {
            r = -1 - lane; v = 0.f; av = 0.f;   // unique sentinels
        }
        float dsum = 0.f, asum = 0.f;
        bool first = true;
        for (int l = 0; l < 64; ++l) {
            int rl = __shfl(r, l);
            float vl = __shfl(v, l);
            float al = __shfl(av, l);
            if (rl == r) {
                dsum += vl; asum += al;
                if (l < lane) first = false;
            }
        }
        float mask = (asum == 1.0f) ? 0.f : asum;   // a_dense==1 -> 0, else count
        float val = dsum + mask;
        float lmax = (mine && first) ? val : -INFINITY;
#pragma unroll
        for (int off = 32; off; off >>= 1) lmax = fmaxf(lmax, __shfl_xor(lmax, off));
        float ex = (mine && first) ? expf(val - lmax) : 0.f;   // each group once
        float lsum = ex;
#pragma unroll
        for (int off = 32; off; off >>= 1) lsum += __shfl_xor(lsum, off);
        float inv = 1.0f / lsum;
        // dup group members hold identical val -> idempotent writes
        if (mine) out[(size_t)r * N + j] = expf(val - lmax) * inv;
    } else {
        // robust path (column degree > 64; ~never at Poisson(32)) — O(m^2)
        float lmax = -INFINITY;
        for (int k = lane; k < m; k += 64) {
            int rk = base[k].x;
            bool first = true;
            float ds = 0.f, as = 0.f;
            for (int l = 0; l < m; ++l) {
                int4 el = base[l];
                if (el.x == rk) {
                    if (l < k) first = false;
                    ds += __int_as_float(el.y);
                    as += __int_as_float(el.z);
                }
            }
            if (first) {
                float mk = (as == 1.0f) ? 0.f : as;
                lmax = fmaxf(lmax, ds + mk);
            }
        }
#pragma unroll
        for (int off = 32; off; off >>= 1) lmax = fmaxf(lmax, __shfl_xor(lmax, off));
        float lsum = 0.f;
        for (int k = lane; k < m; k += 64) {
            int rk = base[k].x;
            bool first = true;
            float ds = 0.f, as = 0.f;
            for (int l = 0; l < m; ++l) {
                int4 el = base[l];
                if (el.x == rk) {
                    if (l < k) first = false;
                    ds += __int_as_float(el.y);
                    as += __int_as_float(el.z);
                }
            }
            if (first) {
                float mk = (as == 1.0f) ? 0.f : as;
                lsum += expf(ds + mk - lmax);
            }
        }
#pragma unroll
        for (int off = 32; off; off >>= 1) lsum += __shfl_xor(lsum, off);
        float inv = 1.0f / lsum;
        for (int k = lane; k < m; k += 64) {
            int rk = base[k].x;
            float ds = 0.f, as = 0.f;
            for (int l = 0; l < m; ++l) {
                int4 el = base[l];
                if (el.x == rk) {
                    ds += __int_as_float(el.y);
                    as += __int_as_float(el.z);
                }
            }
            float mk = (as == 1.0f) ? 0.f : as;
            out[(size_t)rk * N + j] = expf(ds + mk - lmax) * inv;  // idempotent
        }
    }
}

extern "C" void kernel_launch(void* const* d_in, const int* in_sizes, int n_in,
                              void* d_out, int out_size, void* d_ws, size_t ws_size,
                              hipStream_t stream) {
    const float* x = (const float*)d_in[0];
    const int* edges = (const int*)d_in[1];      // harness: integer inputs are int32
    const float* values = (const float*)d_in[2];
    const float* W = (const float*)d_in[3];
    const float* a = (const float*)d_in[4];
    const float* lin_w = (const float*)d_in[5];
    const float* lin_b = (const float*)d_in[6];
    float* out = (float*)d_out;

    int N = in_sizes[0] / S;   // 8192
    int E = in_sizes[2];       // 262144

    // workspace carve (256B-aligned slabs)
    char* wsb = (char*)d_ws;
    size_t off = 0;
    auto alloc = [&](size_t bytes) -> void* {
        void* p = wsb + off;
        off += (bytes + 255) & ~(size_t)255;
        return p;
    };
    float4* s_src4 = (float4*)alloc((size_t)N * 16);
    float4* s_dst4 = (float4*)alloc((size_t)N * 16);
    int* col_cursor = (int*)alloc((size_t)N * 4);
    int4* col_ent = (int4*)alloc((size_t)N * CAP * 16);

    size_t n4tot = (size_t)N * N / 4;
    k1_zero_scores<<<2048, 256, 0, stream>>>(x, W, a, s_src4, s_dst4,
                                             col_cursor, (float4*)out, N, n4tot);
    k2_scatter<<<(E + 255) / 256, 256, 0, stream>>>(edges, values, s_src4, s_dst4,
                                                    lin_w, lin_b, col_cursor, col_ent, N, E);
    k3_softmax<<<(N + 3) / 4, 256, 0, stream>>>(col_ent, col_cursor, out, N);
}